// Round 7
// baseline (7815.134 us; speedup 1.0000x reference)
//
#include <hip/hip_runtime.h>
#include <hip/hip_bf16.h>

typedef __bf16 v8bf __attribute__((ext_vector_type(8)));

// ---- K/Q linear: K[n][o][b] = sum_c W[o,c] X[n,c,b] + bias[o] ----
// X,W,bias fp32; K stored bf16. grid (8 b-tiles, 64 o-tiles, 8 n), block 256.
__global__ __launch_bounds__(256)
void lin_ob(const float* __restrict__ X, const float* __restrict__ W,
            const float* __restrict__ bias, __bf16* __restrict__ K) {
  const int tid = threadIdx.x;
  const int b = blockIdx.x * 256 + tid;
  const int o0 = blockIdx.y * 16;
  const long n = blockIdx.z;
  const float* Xp = X + n * (1024L * 2048) + b;
  float acc[16];
#pragma unroll
  for (int i = 0; i < 16; ++i) acc[i] = bias[o0 + i];
  for (int c = 0; c < 1024; ++c) {
    const float x = Xp[(long)c * 2048];              // coalesced fp32
#pragma unroll
    for (int i = 0; i < 16; ++i)
      acc[i] += x * W[(long)(o0 + i) * 1024 + c];    // thread-uniform
  }
  __bf16* Kp = K + n * (1024L * 2048) + b;
#pragma unroll
  for (int i = 0; i < 16; ++i) {
    float v = fminf(fmaxf(acc[i], -32.f), 32.f);     // |K|<=~6 truly
    Kp[(long)(o0 + i) * 2048] = (__bf16)v;           // coalesced
  }
}

// ---- column sum-of-squares over o: D2[n][b] = sum_o K[n][o][b]^2 ----
__global__ __launch_bounds__(256)
void colnorm2(const __bf16* __restrict__ K, float* __restrict__ D2) {
  const int b = blockIdx.x * 256 + threadIdx.x;
  const long n = blockIdx.y;
  const __bf16* p = K + n * (1024L * 2048) + b;
  float s = 0.f;
  for (int o = 0; o < 1024; ++o) {
    const float f = (float)p[(long)o * 2048];
    s += f * f;
  }
  D2[n * 2048 + b] = s;
}

// ---- scores: YT[n][k][b] = (sum_o Q[o,b] K[o,k]) * rsqrt(max(DQ2[b]*DK2[k],eps)) ----
// grid (8 b-tiles, 128 k-tiles, 8 n), block 256. Thread owns one b (query).
__global__ __launch_bounds__(256)
void scores(const __bf16* __restrict__ K, const __bf16* __restrict__ Q,
            const float* __restrict__ DK2, const float* __restrict__ DQ2,
            __bf16* __restrict__ YT) {
  const int tid = threadIdx.x;
  const int b = blockIdx.x * 256 + tid;
  const int k0 = blockIdx.y * 16;
  const long n = blockIdx.z;
  const __bf16* Qp = Q + n * (1024L * 2048) + b;
  const __bf16* Kp = K + n * (1024L * 2048);
  float acc[16];
#pragma unroll
  for (int i = 0; i < 16; ++i) acc[i] = 0.f;
  for (int o = 0; o < 1024; ++o) {
    const float q = (float)Qp[(long)o * 2048];       // coalesced
#pragma unroll
    for (int i = 0; i < 16; ++i)
      acc[i] += q * (float)Kp[(long)o * 2048 + k0 + i];  // thread-uniform
  }
  const float dq = DQ2[n * 2048 + b];
  __bf16* Yp = YT + n * (2048L * 2048) + b;
#pragma unroll
  for (int i = 0; i < 16; ++i) {
    float v = acc[i] * rsqrtf(fmaxf(dq * DK2[n * 2048 + k0 + i], 1e-12f));
    v = fminf(fmaxf(v, -4.f), 4.f);                  // |Y|<=1 mathematically
    Yp[(long)(k0 + i) * 2048] = (__bf16)v;           // coalesced
  }
}

// ---- in-place row softmax over 2048 bf16 (|Y|<=4: no max pass needed) ----
__global__ __launch_bounds__(256)
void softmax_rows(__bf16* __restrict__ Y) {
  const int tid = threadIdx.x;
  const long row = (long)blockIdx.y * gridDim.x + blockIdx.x;
  __bf16* p = Y + row * 2048;
  v8bf v = *(const v8bf*)&p[tid * 8];
  float f[8];
  float s = 0.f;
#pragma unroll
  for (int u = 0; u < 8; ++u) { f[u] = __expf((float)v[u]); s += f[u]; }
#pragma unroll
  for (int off = 32; off > 0; off >>= 1) s += __shfl_down(s, off);
  __shared__ float red[4];
  __shared__ float stot;
  if ((tid & 63) == 0) red[tid >> 6] = s;
  __syncthreads();
  if (tid == 0) stot = 1.f / (red[0] + red[1] + red[2] + red[3]);
  __syncthreads();
  const float inv = stot;
  v8bf o;
#pragma unroll
  for (int u = 0; u < 8; ++u) o[u] = (__bf16)(f[u] * inv);
  *(v8bf*)&p[tid * 8] = o;
}

// ---- 2048x2048 transpose per n: D[x][y] = S[y][x], 64x64 tiles via LDS ----
__global__ __launch_bounds__(256)
void transpose64(const __bf16* __restrict__ S, __bf16* __restrict__ D) {
  __shared__ __bf16 t[64][72];
  const int c0 = blockIdx.x * 64, r0 = blockIdx.y * 64;
  const long n = blockIdx.z;
  const __bf16* Sp = S + n * (2048L * 2048);
  __bf16* Dp = D + n * (2048L * 2048);
  const int tid = threadIdx.x;
  const int rr = tid >> 3, c8 = (tid & 7) * 8;
#pragma unroll
  for (int it = 0; it < 2; ++it) {
    const int r = rr + it * 32;
    *(v8bf*)&t[r][c8] = *(const v8bf*)&Sp[(long)(r0 + r) * 2048 + c0 + c8];
  }
  __syncthreads();
#pragma unroll
  for (int it = 0; it < 2; ++it) {
    const int rc = rr + it * 32;
    v8bf o;
#pragma unroll
    for (int u = 0; u < 8; ++u) o[u] = t[c8 + u][rc];
    *(v8bf*)&Dp[(long)(c0 + rc) * 2048 + r0 + c8] = o;
  }
}

// ---- Z[n][c][k] = sum_b X[n,c,b] * SM2[n][b][k] ----  X fp32, SM2 bf16, Z FP32
// grid (8 k-tiles, 64 c-tiles, 8 n), block 256. Thread owns one k.
__global__ __launch_bounds__(256)
void zout(const float* __restrict__ X, const __bf16* __restrict__ SM2,
          float* __restrict__ Z) {
  const int tid = threadIdx.x;
  const int k = blockIdx.x * 256 + tid;
  const int c0 = blockIdx.y * 16;
  const long n = blockIdx.z;
  const __bf16* Sp = SM2 + n * (2048L * 2048) + k;
  const float* Xp = X + n * (1024L * 2048);
  float acc[16];
#pragma unroll
  for (int i = 0; i < 16; ++i) acc[i] = 0.f;
  for (int b = 0; b < 2048; ++b) {
    const float s = (float)Sp[(long)b * 2048];       // coalesced
#pragma unroll
    for (int i = 0; i < 16; ++i)
      acc[i] += s * Xp[(long)(c0 + i) * 2048 + b];   // thread-uniform fp32
  }
  float* Zp = Z + n * (1024L * 2048) + k;
#pragma unroll
  for (int i = 0; i < 16; ++i) {
    float v = fminf(fmaxf(acc[i], -1.f), 1.f);       // |Z|<=~0.11 truly
    Zp[(long)(c0 + i) * 2048] = v;                   // coalesced fp32 store
  }
}

extern "C" void kernel_launch(void* const* d_in, const int* in_sizes, int n_in,
                              void* d_out, int out_size, void* d_ws, size_t ws_size,
                              hipStream_t stream) {
  // Inputs FP32 (R4 clamp-saturation logic + R5 delta). Output FP32 (reference
  // returns float32; the "(bf16)" label / bf16-grid ref max come from the
  // harness bf16-ROUNDING the np reference for thresholding, not from d_out's
  // dtype — this round's single flipped variable).
  const float* X    = (const float*)d_in[0];
  const float* Wk_w = (const float*)d_in[1];
  const float* Wk_b = (const float*)d_in[2];
  const float* Wq_w = (const float*)d_in[3];
  const float* Wq_b = (const float*)d_in[4];
  float* out = (float*)d_out;

  // ws: K 32M | Q 32M | YT 64M = exactly 128 MiB.
  char* ws = (char*)d_ws;
  __bf16* K   = (__bf16*)(ws);
  __bf16* Q   = (__bf16*)(ws + 33554432L);
  __bf16* YT  = (__bf16*)(ws + 67108864L);
  __bf16* SM2 = (__bf16*)(ws);   // overlays K+Q (dead after scores)
  // DK2/DQ2 in d_out (64 MiB as fp32); zout fully overwrites d_out at the end
  // and never reads it, so no hazard.
  float* DK2 = (float*)d_out;
  float* DQ2 = (float*)d_out + 16384;

  lin_ob<<<dim3(8, 64, 8), 256, 0, stream>>>(X, Wk_w, Wk_b, K);
  lin_ob<<<dim3(8, 64, 8), 256, 0, stream>>>(X, Wq_w, Wq_b, Q);
  colnorm2<<<dim3(8, 8), 256, 0, stream>>>(K, DK2);
  colnorm2<<<dim3(8, 8), 256, 0, stream>>>(Q, DQ2);
  scores<<<dim3(8, 128, 8), 256, 0, stream>>>(K, Q, DK2, DQ2, YT);
  softmax_rows<<<dim3(2048, 8), 256, 0, stream>>>(YT);
  transpose64<<<dim3(32, 32, 8), 256, 0, stream>>>(YT, SM2);
  zout<<<dim3(8, 64, 8), 256, 0, stream>>>(X, SM2, out);
}

// Round 8
// 452.288 us; speedup vs baseline: 17.2791x; 17.2791x over previous
//
#include <hip/hip_runtime.h>
#include <hip/hip_bf16.h>

typedef __bf16 v8bf __attribute__((ext_vector_type(8)));
typedef __bf16 v4bf __attribute__((ext_vector_type(4)));
typedef float  v4f  __attribute__((ext_vector_type(4)));

#define AS1 __attribute__((address_space(1)))
#define AS3 __attribute__((address_space(3)))

static __device__ __forceinline__ void gload_lds16(const void* g, void* l) {
  __builtin_amdgcn_global_load_lds((const AS1 void*)g, (AS3 void*)l, 16, 0, 0);
}

// ---- elementwise fp32 -> bf16 (n multiple of 4) ----
__global__ __launch_bounds__(256)
void cvt_bf16(const float* __restrict__ in, __bf16* __restrict__ out, long n) {
  const long i = ((long)blockIdx.x * 256 + threadIdx.x) * 4;
  if (i >= n) return;
  v4f v = *(const v4f*)&in[i];
  v4bf o;
#pragma unroll
  for (int u = 0; u < 4; ++u) o[u] = (__bf16)v[u];
  *(v4bf*)&out[i] = o;
}

// ---- X [n][c][b] fp32 -> XT [n][b][c] bf16, 64x64 tiles via LDS ----
// grid (32 b-tiles, 16 c-tiles, 8)
__global__ __launch_bounds__(256)
void cvt_transpose(const float* __restrict__ X, __bf16* __restrict__ XT) {
  __shared__ float t[64][65];
  const int b0 = blockIdx.x * 64, c0 = blockIdx.y * 64;
  const long n = blockIdx.z;
  const float* Xp = X + n * (1024L * 2048);
  __bf16* Tp = XT + n * (2048L * 1024);
  const int tid = threadIdx.x;
  const int r16 = tid >> 4, c4 = (tid & 15) * 4;
#pragma unroll
  for (int it = 0; it < 4; ++it) {
    const int r = r16 + it * 16;   // local c
    *(v4f*)&t[r][c4] = *(const v4f*)&Xp[(long)(c0 + r) * 2048 + b0 + c4];
  }
  __syncthreads();
  const int rb8 = tid >> 3, c8 = (tid & 7) * 8;
#pragma unroll
  for (int it = 0; it < 2; ++it) {
    const int rb = rb8 + it * 32;  // local b
    v8bf o;
#pragma unroll
    for (int u = 0; u < 8; ++u) o[u] = (__bf16)t[c8 + u][rb];
    *(v8bf*)&Tp[(long)(b0 + rb) * 1024 + c0 + c8] = o;
  }
}

// ---- TN GEMM: out[m,n] = sum_k A[m,k]*BT[n,k], 128x128 tile, bf16 MFMA ----
// m97-style global_load_lds staging (width 16).
// EPI 0: += bias[col], clamp +-32 ; EPI 1: *= rsqrt(max(dk2[row]*dq2[col],eps)), clamp +-4
// EPI 2: clamp +-1. OT = output type.
template<int KD, int EPI, typename OT>
__global__ __launch_bounds__(256, 2)
void gemm_tn(const __bf16* __restrict__ Abase, const __bf16* __restrict__ Bbase,
             OT* __restrict__ Obase,
             const __bf16* __restrict__ bias,
             const float* __restrict__ dk2, const float* __restrict__ dq2,
             long sA, long sB, long sO) {
  __shared__ __bf16 At[128 * 32];
  __shared__ __bf16 Bt[128 * 32];

  const int tid = threadIdx.x;
  const int wave = tid >> 6, lane = tid & 63;
  const int n0 = blockIdx.x * 128, m0 = blockIdx.y * 128;
  const long z = blockIdx.z;

  const __bf16* A = Abase + z * sA + (long)m0 * KD;
  const __bf16* B = Bbase + z * sB + (long)n0 * KD;

  v4f acc[4][4];
#pragma unroll
  for (int i = 0; i < 4; ++i)
#pragma unroll
    for (int j = 0; j < 4; ++j) acc[i][j] = {0.f, 0.f, 0.f, 0.f};

  const int wr = wave >> 1, wc = wave & 1;
  const int fr = lane & 15, q = lane >> 4;

  // staging slot e covers LDS halfs [e*8, e*8+8) = tile row (e>>2), k-chunk (e&3)*8
  const int e0 = wave * 64 + lane;
  const int e1 = e0 + 256;
  const int r0 = e0 >> 2, kq0 = (e0 & 3) * 8;
  const int r1 = e1 >> 2, kq1 = (e1 & 3) * 8;
  __bf16* ldsA0 = &At[wave * 512];          // wave-uniform bases; lane i -> +16B*i
  __bf16* ldsA1 = &At[wave * 512 + 2048];
  __bf16* ldsB0 = &Bt[wave * 512];
  __bf16* ldsB1 = &Bt[wave * 512 + 2048];

  for (int kt = 0; kt < KD / 32; ++kt) {
    const int kb = kt * 32;
    __syncthreads();
    gload_lds16(A + (long)r0 * KD + kb + kq0, ldsA0);
    gload_lds16(A + (long)r1 * KD + kb + kq1, ldsA1);
    gload_lds16(B + (long)r0 * KD + kb + kq0, ldsB0);
    gload_lds16(B + (long)r1 * KD + kb + kq1, ldsB1);
    __syncthreads();

    v8bf af[4], bf[4];
#pragma unroll
    for (int i = 0; i < 4; ++i)
      af[i] = *(const v8bf*)&At[(wr * 64 + i * 16 + fr) * 32 + q * 8];
#pragma unroll
    for (int j = 0; j < 4; ++j)
      bf[j] = *(const v8bf*)&Bt[(wc * 64 + j * 16 + fr) * 32 + q * 8];
#pragma unroll
    for (int i = 0; i < 4; ++i)
#pragma unroll
      for (int j = 0; j < 4; ++j)
        acc[i][j] = __builtin_amdgcn_mfma_f32_16x16x32_bf16(af[i], bf[j], acc[i][j], 0, 0, 0);
  }

  OT* O = Obase + z * sO;
  const int ldo = gridDim.x * 128;
#pragma unroll
  for (int j = 0; j < 4; ++j) {
    const int col = n0 + wc * 64 + j * 16 + fr;
    float cv = 0.f;
    if (EPI == 0) cv = (float)bias[col];
    if (EPI == 1) cv = dq2[z * 2048 + col];
#pragma unroll
    for (int i = 0; i < 4; ++i) {
      const int row0 = m0 + wr * 64 + i * 16 + q * 4;
#pragma unroll
      for (int r = 0; r < 4; ++r) {
        float v = acc[i][j][r];
        const int row = row0 + r;
        if (EPI == 0) v = fminf(fmaxf(v + cv, -32.f), 32.f);
        if (EPI == 1) {
          v *= rsqrtf(fmaxf(dk2[z * 2048 + row] * cv, 1e-12f));
          v = fminf(fmaxf(v, -4.f), 4.f);
        }
        if (EPI == 2) v = fminf(fmaxf(v, -1.f), 1.f);
        O[(long)row * ldo + col] = (OT)v;
      }
    }
  }
}

// ---- row sum-of-squares: contiguous rows of 1024 bf16 -> out[row] ----
__global__ __launch_bounds__(256)
void rownorm2(const __bf16* __restrict__ T, float* __restrict__ out) {
  const int tid = threadIdx.x;
  const long row = (long)blockIdx.y * gridDim.x + blockIdx.x;
  const __bf16* p = T + row * 1024;
  v4bf v = *(const v4bf*)&p[tid * 4];
  float s = 0.f;
#pragma unroll
  for (int u = 0; u < 4; ++u) { float f = (float)v[u]; s += f * f; }
#pragma unroll
  for (int off = 32; off > 0; off >>= 1) s += __shfl_down(s, off);
  __shared__ float red[4];
  if ((tid & 63) == 0) red[tid >> 6] = s;
  __syncthreads();
  if (tid == 0) out[row] = red[0] + red[1] + red[2] + red[3];
}

// ---- in-place row softmax over 2048 bf16 (|Y|<=4: no max pass) ----
__global__ __launch_bounds__(256)
void softmax_rows(__bf16* __restrict__ Y) {
  const int tid = threadIdx.x;
  const long row = (long)blockIdx.y * gridDim.x + blockIdx.x;
  __bf16* p = Y + row * 2048;
  v8bf v = *(const v8bf*)&p[tid * 8];
  float f[8];
  float s = 0.f;
#pragma unroll
  for (int u = 0; u < 8; ++u) { f[u] = __expf((float)v[u]); s += f[u]; }
#pragma unroll
  for (int off = 32; off > 0; off >>= 1) s += __shfl_down(s, off);
  __shared__ float red[4];
  __shared__ float stot;
  if ((tid & 63) == 0) red[tid >> 6] = s;
  __syncthreads();
  if (tid == 0) stot = 1.f / (red[0] + red[1] + red[2] + red[3]);
  __syncthreads();
  const float inv = stot;
  v8bf o;
#pragma unroll
  for (int u = 0; u < 8; ++u) o[u] = (__bf16)(f[u] * inv);
  *(v8bf*)&p[tid * 8] = o;
}

extern "C" void kernel_launch(void* const* d_in, const int* in_sizes, int n_in,
                              void* d_out, int out_size, void* d_ws, size_t ws_size,
                              hipStream_t stream) {
  // Inputs fp32, output fp32 (confirmed R7 PASS).
  const float* X    = (const float*)d_in[0];
  const float* Wk_w = (const float*)d_in[1];
  const float* Wk_b = (const float*)d_in[2];
  const float* Wq_w = (const float*)d_in[3];
  const float* Wq_b = (const float*)d_in[4];
  float* out = (float*)d_out;

  // ws (<=100.2 MiB of the verified 128 MiB):
  //   [0,32M): XT bf16 [n][b][c]  -> later Xbf bf16 [n][c][b]
  //   [32M,96M): YT bf16 [n][k][b]
  //   [96M+): DK2, DQ2 (64K each), Wk_bf, Wq_bf (2M each), bk_bf, bq_bf (2K each)
  char* ws = (char*)d_ws;
  __bf16* XT  = (__bf16*)(ws);
  __bf16* Xbf = (__bf16*)(ws);
  __bf16* YT  = (__bf16*)(ws + 33554432L);
  char* aux   = ws + 100663296L;
  float*  DK2   = (float*)(aux);
  float*  DQ2   = (float*)(aux + 65536L);
  __bf16* Wk_bf = (__bf16*)(aux + 131072L);
  __bf16* Wq_bf = (__bf16*)(aux + 131072L + 2097152L);
  __bf16* bk_bf = (__bf16*)(aux + 131072L + 4194304L);
  __bf16* bq_bf = (__bf16*)(aux + 131072L + 4196352L);
  // d_out (64 MiB) holds KT|QT until GEMM3 overwrites it with Z.
  __bf16* KT = (__bf16*)d_out;
  __bf16* QT = (__bf16*)((char*)d_out + 33554432L);

  // 0) convert weights/biases to bf16
  cvt_bf16<<<1024, 256, 0, stream>>>(Wk_w, Wk_bf, 1048576L);
  cvt_bf16<<<1024, 256, 0, stream>>>(Wq_w, Wq_bf, 1048576L);
  cvt_bf16<<<1, 256, 0, stream>>>(Wk_b, bk_bf, 1024L);
  cvt_bf16<<<1, 256, 0, stream>>>(Wq_b, bq_bf, 1024L);
  // 1) XT[n][b][c] = (bf16) X[n][c][b]
  cvt_transpose<<<dim3(32, 16, 8), 256, 0, stream>>>(X, XT);
  // 2) KT[n][b][o] = XT[b,:]·Wk[o,:] + bk[o]; same for QT
  gemm_tn<1024, 0, __bf16><<<dim3(8, 16, 8), 256, 0, stream>>>(
      XT, Wk_bf, KT, bk_bf, nullptr, nullptr, 2048L * 1024, 0L, 2048L * 1024);
  gemm_tn<1024, 0, __bf16><<<dim3(8, 16, 8), 256, 0, stream>>>(
      XT, Wq_bf, QT, bq_bf, nullptr, nullptr, 2048L * 1024, 0L, 2048L * 1024);
  // 3) Xbf = (bf16) X  (XT dead; same ws region)
  cvt_bf16<<<16384, 256, 0, stream>>>(X, Xbf, 16777216L);
  // 4) DK2[n][b] = |KT[b,:]|^2 ; DQ2 likewise
  rownorm2<<<dim3(2048, 8), 256, 0, stream>>>(KT, DK2);
  rownorm2<<<dim3(2048, 8), 256, 0, stream>>>(QT, DQ2);
  // 5) YT[n][k][b] = (KT[k,:]·QT[b,:]) * rsqrt(max(DK2[k]*DQ2[b],eps))
  gemm_tn<1024, 1, __bf16><<<dim3(16, 16, 8), 256, 0, stream>>>(
      KT, QT, YT, nullptr, DK2, DQ2, 2048L * 1024, 2048L * 1024, 2048L * 2048);
  // 6) softmax over b within each YT row (ref softmax over query axis)
  softmax_rows<<<dim3(2048, 8), 256, 0, stream>>>(YT);
  // 7) Z[n][c][k] = Xbf[c,:]·SMT[k,:]  (sum over b) -> d_out fp32
  gemm_tn<2048, 2, float><<<dim3(16, 8, 8), 256, 0, stream>>>(
      Xbf, YT, out, nullptr, nullptr, nullptr, 1024L * 2048, 2048L * 2048, 1024L * 2048);
}